// Round 1
// baseline (11.527 us; speedup 1.0000x reference)
//
#include <hip/hip_runtime.h>
#include <hip/hip_bf16.h>

#define PI_F 3.1415926f

__device__ __forceinline__ void pts_dec(float r, float h, float w, float l,
                                        float lx, float ly, float lz,
                                        float px[8], float py[8], float pz[8]) {
    // XS = {1,1,-1,-1,1,1,-1,-1}, YS = {0,0,0,0,1,1,1,1}, ZS = {1,-1,-1,1,1,-1,-1,1}
    const float XS[8] = {1.f, 1.f, -1.f, -1.f, 1.f, 1.f, -1.f, -1.f};
    const float YS[8] = {0.f, 0.f, 0.f, 0.f, 1.f, 1.f, 1.f, 1.f};
    const float ZS[8] = {1.f, -1.f, -1.f, 1.f, 1.f, -1.f, -1.f, 1.f};
    float c = cosf(r), s = sinf(r);
#pragma unroll
    for (int j = 0; j < 8; ++j) {
        float cx = 0.5f * l * XS[j];
        float cy = -w * YS[j];
        float cz = 0.5f * h * ZS[j];
        px[j] = c * cx + s * cz + lx;
        py[j] = cy + ly;
        pz[j] = -s * cx + c * cz + lz;
    }
}

__global__ void __launch_bounds__(128)
decode_loss_partial(const float* __restrict__ output,   // (64,8,128,416)
                    const int*   __restrict__ ind,      // (64,128)
                    const int*   __restrict__ cls_id,   // (64,128)
                    const int*   __restrict__ reg_mask, // (64,128)
                    const int*   __restrict__ flip_mask,// (64,128)
                    const float* __restrict__ ct3d,     // (64,128,2)
                    const float* __restrict__ reg3d,    // (64,128,8)
                    const float* __restrict__ roty,     // (64,128)
                    const float* __restrict__ Kmat,     // (64,3,4)
                    const float* __restrict__ trans,    // (64,2,3)
                    float* __restrict__ partial)        // (64)
{
    const int b = blockIdx.x;        // image
    const int k = threadIdx.x;       // object within image
    const int n = b * 128 + k;
    const int HW = 128 * 416;

    float local = 0.f;

    if (reg_mask[n] != 0) {
        // ---- gather pred (output[b, c, ind]) and tgt ----
        const int idx = ind[n];
        const float* outb = output + (size_t)b * 8 * HW + idx;
        float pred[8], tgt[8];
#pragma unroll
        for (int c = 0; c < 8; ++c) pred[c] = outb[(size_t)c * HW];
#pragma unroll
        for (int c = 0; c < 8; ++c) tgt[c] = reg3d[n * 8 + c];

        const int cls = cls_id[n];
        const float fm = (float)flip_mask[n];

        // ---- per-image inverses (analytic) ----
        // trans_inv: inverse of [[t0,t1,t2],[t3,t4,t5],[0,0,1]]
        const float* t = trans + b * 6;
        float det2 = t[0] * t[4] - t[1] * t[3];
        float rdet2 = 1.f / det2;
        float ta =  t[4] * rdet2, tb = -t[1] * rdet2;
        float td = -t[3] * rdet2, te =  t[0] * rdet2;
        float tc = -(ta * t[2] + tb * t[5]);
        float tf = -(td * t[2] + te * t[5]);

        // K_inv: general 3x3 inverse of K[:, :3]
        const float* Km = Kmat + b * 12;
        float m00 = Km[0], m01 = Km[1], m02 = Km[2];
        float m10 = Km[4], m11 = Km[5], m12 = Km[6];
        float m20 = Km[8], m21 = Km[9], m22 = Km[10];
        float det = m00 * (m11 * m22 - m12 * m21)
                  - m01 * (m10 * m22 - m12 * m20)
                  + m02 * (m10 * m21 - m11 * m20);
        float rdet = 1.f / det;
        float i00 = (m11 * m22 - m12 * m21) * rdet;
        float i01 = (m02 * m21 - m01 * m22) * rdet;
        float i02 = (m01 * m12 - m02 * m11) * rdet;
        float i10 = (m12 * m20 - m10 * m22) * rdet;
        float i11 = (m00 * m22 - m02 * m20) * rdet;
        float i12 = (m02 * m10 - m00 * m12) * rdet;
        float i20 = (m10 * m21 - m11 * m20) * rdet;
        float i21 = (m01 * m20 - m00 * m21) * rdet;
        float i22 = (m00 * m11 - m01 * m10) * rdet;

        // ---- depths ----
        float pd = pred[0] * 16.32f + 28.01f;
        float gd = tgt[0]  * 16.32f + 28.01f;

        // ---- loc_dec ----
        float ct0 = ct3d[n * 2 + 0], ct1 = ct3d[n * 2 + 1];
        auto loc_dec = [&](float ox, float oy, float depth,
                           float& lx, float& ly, float& lz) {
            float cx = ct0 + ox, cy = ct1 + oy;
            float u0 = ta * cx + tb * cy + tc;
            float u1 = td * cx + te * cy + tf;
            float g0 = u0 * depth, g1 = u1 * depth, g2 = depth;
            lx = i00 * g0 + i01 * g1 + i02 * g2;
            ly = i10 * g0 + i11 * g1 + i12 * g2;
            lz = i20 * g0 + i21 * g1 + i22 * g2;
        };
        float plx, ply, plz, glx, gly, glz;
        loc_dec(pred[1], pred[2], pd, plx, ply, plz);
        loc_dec(tgt[1],  tgt[2],  gd, glx, gly, glz);

        // ---- dim_dec ----
        const float DIMS_AVG[3][3] = {{1.63f, 1.53f, 3.88f},
                                      {1.73f, 0.67f, 0.88f},
                                      {1.7f,  0.58f, 1.78f}};
        float ph = expf(pred[3]) * DIMS_AVG[cls][0];
        float pw = expf(pred[4]) * DIMS_AVG[cls][1];
        float pl = expf(pred[5]) * DIMS_AVG[cls][2];
        float gh = expf(tgt[3]) * DIMS_AVG[cls][0];
        float gw = expf(tgt[4]) * DIMS_AVG[cls][1];
        float gl = expf(tgt[5]) * DIMS_AVG[cls][2];

        ply += ph * 0.5f;
        gly += gh * 0.5f;

        // ---- ori_dec (uses g_loc after y-adjust; x,z unaffected anyway) ----
        float off = atanf(glx / glz + 1e-7f);
        float alpha = atanf(pred[6] / (pred[7] + 1e-7f));
        alpha += (pred[7] >= 0.f) ? -PI_F * 0.5f : PI_F * 0.5f;
        float r = alpha + off;
        if (r > PI_F)       r -= 2.f * PI_F;
        else if (r < -PI_F) r += 2.f * PI_F;
        float p_roty;
        if (fm != 0.f) {
            float rf = r;
            if (rf > 0.f)      rf -= PI_F;
            else if (rf < 0.f) rf += PI_F;
            p_roty = rf;
        } else {
            p_roty = r;
        }
        float g_roty = roty[n];  // reg_mask == 1 here

        // ---- three pts_dec terms vs gt_box ----
        float gx[8], gy[8], gz[8];
        pts_dec(g_roty, gh, gw, gl, glx, gly, glz, gx, gy, gz);

        float ax[8], ay[8], az[8];
        float s = 0.f;

        // term 1: rotation from pred
        pts_dec(p_roty, gh, gw, gl, glx, gly, glz, ax, ay, az);
#pragma unroll
        for (int j = 0; j < 8; ++j)
            s += fabsf(ax[j] - gx[j]) + fabsf(ay[j] - gy[j]) + fabsf(az[j] - gz[j]);

        // term 2: dims from pred
        pts_dec(g_roty, ph, pw, pl, glx, gly, glz, ax, ay, az);
#pragma unroll
        for (int j = 0; j < 8; ++j)
            s += fabsf(ax[j] - gx[j]) + fabsf(ay[j] - gy[j]) + fabsf(az[j] - gz[j]);

        // term 3: location from pred
        pts_dec(g_roty, gh, gw, gl, plx, ply, plz, ax, ay, az);
#pragma unroll
        for (int j = 0; j < 8; ++j)
            s += fabsf(ax[j] - gx[j]) + fabsf(ay[j] - gy[j]) + fabsf(az[j] - gz[j]);

        local = s;
    }

    // ---- block reduction (2 waves of 64) ----
#pragma unroll
    for (int o = 32; o > 0; o >>= 1) local += __shfl_down(local, o, 64);
    __shared__ float wsum[2];
    if ((threadIdx.x & 63) == 0) wsum[threadIdx.x >> 6] = local;
    __syncthreads();
    if (threadIdx.x == 0) partial[b] = wsum[0] + wsum[1];
}

__global__ void __launch_bounds__(64)
reduce_final(const float* __restrict__ partial, float* __restrict__ out) {
    float v = partial[threadIdx.x];  // 64 partials, one wave
#pragma unroll
    for (int o = 32; o > 0; o >>= 1) v += __shfl_down(v, o, 64);
    if (threadIdx.x == 0) out[0] = v * (1.f / 1280.f);
}

extern "C" void kernel_launch(void* const* d_in, const int* in_sizes, int n_in,
                              void* d_out, int out_size, void* d_ws, size_t ws_size,
                              hipStream_t stream) {
    const float* output    = (const float*)d_in[0];
    const int*   ind       = (const int*)d_in[1];
    const int*   cls_id    = (const int*)d_in[2];
    const int*   reg_mask  = (const int*)d_in[3];
    const int*   flip_mask = (const int*)d_in[4];
    const float* ct3d      = (const float*)d_in[5];
    const float* reg_3d    = (const float*)d_in[6];
    const float* roty      = (const float*)d_in[7];
    const float* K         = (const float*)d_in[8];
    const float* trans     = (const float*)d_in[9];
    float* out = (float*)d_out;
    float* partial = (float*)d_ws;  // 64 floats

    decode_loss_partial<<<64, 128, 0, stream>>>(output, ind, cls_id, reg_mask,
                                                flip_mask, ct3d, reg_3d, roty,
                                                K, trans, partial);
    reduce_final<<<1, 64, 0, stream>>>(partial, out);
}

// Round 2
// 11.020 us; speedup vs baseline: 1.0459x; 1.0459x over previous
//
#include <hip/hip_runtime.h>
#include <hip/hip_bf16.h>

#define PI_F 3.1415926f

__device__ __forceinline__ void pts_dec(float r, float h, float w, float l,
                                        float lx, float ly, float lz,
                                        float px[8], float py[8], float pz[8]) {
    const float XS[8] = {1.f, 1.f, -1.f, -1.f, 1.f, 1.f, -1.f, -1.f};
    const float YS[8] = {0.f, 0.f, 0.f, 0.f, 1.f, 1.f, 1.f, 1.f};
    const float ZS[8] = {1.f, -1.f, -1.f, 1.f, 1.f, -1.f, -1.f, 1.f};
    float c = cosf(r), s = sinf(r);
#pragma unroll
    for (int j = 0; j < 8; ++j) {
        float cx = 0.5f * l * XS[j];
        float cy = -w * YS[j];
        float cz = 0.5f * h * ZS[j];
        px[j] = c * cx + s * cz + lx;
        py[j] = cy + ly;
        pz[j] = -s * cx + c * cz + lz;
    }
}

// 128 blocks x 64 threads: one wave per block, block handles half an image.
__global__ void __launch_bounds__(64)
decode_loss_partial(const float* __restrict__ output,   // (64,8,128,416)
                    const int*   __restrict__ ind,      // (64,128)
                    const int*   __restrict__ cls_id,   // (64,128)
                    const int*   __restrict__ reg_mask, // (64,128)
                    const int*   __restrict__ flip_mask,// (64,128)
                    const float* __restrict__ ct3d,     // (64,128,2)
                    const float* __restrict__ reg3d,    // (64,128,8)
                    const float* __restrict__ roty,     // (64,128)
                    const float* __restrict__ Kmat,     // (64,3,4)
                    const float* __restrict__ trans,    // (64,2,3)
                    float* __restrict__ partial)        // (128)
{
    const int n = blockIdx.x * 64 + threadIdx.x;   // global object id
    const int b = n >> 7;                          // image id
    const int HW = 128 * 416;

    float local = 0.f;

    if (reg_mask[n] != 0) {
        // ---- gather pred (output[b, c, ind]) and tgt ----
        const int idx = ind[n];
        const float* outb = output + (size_t)b * 8 * HW + idx;
        float pred[8], tgt[8];
#pragma unroll
        for (int c = 0; c < 8; ++c) pred[c] = outb[(size_t)c * HW];
#pragma unroll
        for (int c = 0; c < 8; ++c) tgt[c] = reg3d[n * 8 + c];

        const int cls = cls_id[n];
        const float fm = (float)flip_mask[n];

        // ---- per-image inverses (analytic) ----
        const float* t = trans + b * 6;
        float det2 = t[0] * t[4] - t[1] * t[3];
        float rdet2 = 1.f / det2;
        float ta =  t[4] * rdet2, tb = -t[1] * rdet2;
        float td = -t[3] * rdet2, te =  t[0] * rdet2;
        float tc = -(ta * t[2] + tb * t[5]);
        float tf = -(td * t[2] + te * t[5]);

        const float* Km = Kmat + b * 12;
        float m00 = Km[0], m01 = Km[1], m02 = Km[2];
        float m10 = Km[4], m11 = Km[5], m12 = Km[6];
        float m20 = Km[8], m21 = Km[9], m22 = Km[10];
        float det = m00 * (m11 * m22 - m12 * m21)
                  - m01 * (m10 * m22 - m12 * m20)
                  + m02 * (m10 * m21 - m11 * m20);
        float rdet = 1.f / det;
        float i00 = (m11 * m22 - m12 * m21) * rdet;
        float i01 = (m02 * m21 - m01 * m22) * rdet;
        float i02 = (m01 * m12 - m02 * m11) * rdet;
        float i10 = (m12 * m20 - m10 * m22) * rdet;
        float i11 = (m00 * m22 - m02 * m20) * rdet;
        float i12 = (m02 * m10 - m00 * m12) * rdet;
        float i20 = (m10 * m21 - m11 * m20) * rdet;
        float i21 = (m01 * m20 - m00 * m21) * rdet;
        float i22 = (m00 * m11 - m01 * m10) * rdet;

        // ---- depths ----
        float pd = pred[0] * 16.32f + 28.01f;
        float gd = tgt[0]  * 16.32f + 28.01f;

        // ---- loc_dec ----
        float ct0 = ct3d[n * 2 + 0], ct1 = ct3d[n * 2 + 1];
        auto loc_dec = [&](float ox, float oy, float depth,
                           float& lx, float& ly, float& lz) {
            float cx = ct0 + ox, cy = ct1 + oy;
            float u0 = ta * cx + tb * cy + tc;
            float u1 = td * cx + te * cy + tf;
            float g0 = u0 * depth, g1 = u1 * depth, g2 = depth;
            lx = i00 * g0 + i01 * g1 + i02 * g2;
            ly = i10 * g0 + i11 * g1 + i12 * g2;
            lz = i20 * g0 + i21 * g1 + i22 * g2;
        };
        float plx, ply, plz, glx, gly, glz;
        loc_dec(pred[1], pred[2], pd, plx, ply, plz);
        loc_dec(tgt[1],  tgt[2],  gd, glx, gly, glz);

        // ---- dim_dec ----
        const float DIMS_AVG[3][3] = {{1.63f, 1.53f, 3.88f},
                                      {1.73f, 0.67f, 0.88f},
                                      {1.7f,  0.58f, 1.78f}};
        float ph = expf(pred[3]) * DIMS_AVG[cls][0];
        float pw = expf(pred[4]) * DIMS_AVG[cls][1];
        float pl = expf(pred[5]) * DIMS_AVG[cls][2];
        float gh = expf(tgt[3]) * DIMS_AVG[cls][0];
        float gw = expf(tgt[4]) * DIMS_AVG[cls][1];
        float gl = expf(tgt[5]) * DIMS_AVG[cls][2];

        ply += ph * 0.5f;
        gly += gh * 0.5f;

        // ---- ori_dec ----
        float off = atanf(glx / glz + 1e-7f);
        float alpha = atanf(pred[6] / (pred[7] + 1e-7f));
        alpha += (pred[7] >= 0.f) ? -PI_F * 0.5f : PI_F * 0.5f;
        float r = alpha + off;
        if (r > PI_F)       r -= 2.f * PI_F;
        else if (r < -PI_F) r += 2.f * PI_F;
        float p_roty;
        if (fm != 0.f) {
            float rf = r;
            if (rf > 0.f)      rf -= PI_F;
            else if (rf < 0.f) rf += PI_F;
            p_roty = rf;
        } else {
            p_roty = r;
        }
        float g_roty = roty[n];

        // ---- three pts_dec terms vs gt_box ----
        float gx[8], gy[8], gz[8];
        pts_dec(g_roty, gh, gw, gl, glx, gly, glz, gx, gy, gz);

        float ax[8], ay[8], az[8];
        float s = 0.f;

        pts_dec(p_roty, gh, gw, gl, glx, gly, glz, ax, ay, az);
#pragma unroll
        for (int j = 0; j < 8; ++j)
            s += fabsf(ax[j] - gx[j]) + fabsf(ay[j] - gy[j]) + fabsf(az[j] - gz[j]);

        pts_dec(g_roty, ph, pw, pl, glx, gly, glz, ax, ay, az);
#pragma unroll
        for (int j = 0; j < 8; ++j)
            s += fabsf(ax[j] - gx[j]) + fabsf(ay[j] - gy[j]) + fabsf(az[j] - gz[j]);

        pts_dec(g_roty, gh, gw, gl, plx, ply, plz, ax, ay, az);
#pragma unroll
        for (int j = 0; j < 8; ++j)
            s += fabsf(ax[j] - gx[j]) + fabsf(ay[j] - gy[j]) + fabsf(az[j] - gz[j]);

        local = s;
    }

    // ---- single-wave reduction ----
#pragma unroll
    for (int o = 32; o > 0; o >>= 1) local += __shfl_down(local, o, 64);
    if (threadIdx.x == 0) partial[blockIdx.x] = local;
}

__global__ void __launch_bounds__(64)
reduce_final(const float* __restrict__ partial, float* __restrict__ out) {
    float v = partial[threadIdx.x] + partial[threadIdx.x + 64];
#pragma unroll
    for (int o = 32; o > 0; o >>= 1) v += __shfl_down(v, o, 64);
    if (threadIdx.x == 0) out[0] = v * (1.f / 1280.f);
}

extern "C" void kernel_launch(void* const* d_in, const int* in_sizes, int n_in,
                              void* d_out, int out_size, void* d_ws, size_t ws_size,
                              hipStream_t stream) {
    const float* output    = (const float*)d_in[0];
    const int*   ind       = (const int*)d_in[1];
    const int*   cls_id    = (const int*)d_in[2];
    const int*   reg_mask  = (const int*)d_in[3];
    const int*   flip_mask = (const int*)d_in[4];
    const float* ct3d      = (const float*)d_in[5];
    const float* reg_3d    = (const float*)d_in[6];
    const float* roty      = (const float*)d_in[7];
    const float* K         = (const float*)d_in[8];
    const float* trans     = (const float*)d_in[9];
    float* out = (float*)d_out;
    float* partial = (float*)d_ws;  // 128 floats

    decode_loss_partial<<<128, 64, 0, stream>>>(output, ind, cls_id, reg_mask,
                                                flip_mask, ct3d, reg_3d, roty,
                                                K, trans, partial);
    reduce_final<<<1, 64, 0, stream>>>(partial, out);
}